// Round 1
// baseline (168.686 us; speedup 1.0000x reference)
//
#include <hip/hip_runtime.h>

#define T_LEN 1024
#define NSTEP 1023   // steps k = 0..1022

// R = exp(skew(p)) = I + A*K + B*K^2
__device__ __forceinline__ void so3_exp(float px, float py, float pz, float R[9]) {
    float t2 = px * px + py * py + pz * pz;
    float A, Bc;
    if (t2 < 1e-2f) {
        // Taylor: exact to ~1e-10 rel for theta < 0.1 (our theta <= ~0.02)
        float t4 = t2 * t2;
        A  = 1.0f - t2 * (1.0f / 6.0f)  + t4 * (1.0f / 120.0f);
        Bc = 0.5f - t2 * (1.0f / 24.0f) + t4 * (1.0f / 720.0f);
    } else {
        float th = sqrtf(t2);
        A = __sinf(th) / th;
        float sh = __sinf(0.5f * th);
        Bc = 2.0f * sh * sh / t2;   // (1-cos)/t2 without cancellation
    }
    float xx = px * px, yy = py * py, zz = pz * pz;
    float xy = px * py, xz = px * pz, yz = py * pz;
    R[0] = 1.0f - Bc * (yy + zz);
    R[1] = Bc * xy - A * pz;
    R[2] = Bc * xz + A * py;
    R[3] = Bc * xy + A * pz;
    R[4] = 1.0f - Bc * (xx + zz);
    R[5] = Bc * yz - A * px;
    R[6] = Bc * xz - A * py;
    R[7] = Bc * yz + A * px;
    R[8] = 1.0f - Bc * (xx + yy);
}

// One block per batch row. 256 threads x 4 steps = 1024 >= 1023 steps.
// Element e = (C[9], V[3], R[3], tau): state action R+=V*tau_e + C*r_e; V+=C*v_e; C=C*M_e.
// Compose left-to-right with adjacent-pair tree (non-commutative!).
extern "C" __global__ void __launch_bounds__(256)
rmi_kernel(const float* __restrict__ x, float* __restrict__ out) {
    const int b   = blockIdx.x;
    const int tid = threadIdx.x;
    const float* __restrict__ xb = x + (size_t)b * (7 * T_LEN);

    __shared__ float s[256 * 17];   // 16 payload + 1 pad (bank-conflict-free)

    // ---- coalesced vector loads: 4 steps per thread ----
    const int k0 = tid * 4;
    float4 t4  = *reinterpret_cast<const float4*>(xb + k0);
    float  tn  = (k0 + 4 < T_LEN) ? xb[k0 + 4] : 0.0f;
    float4 wx4 = *reinterpret_cast<const float4*>(xb + 1 * T_LEN + k0);
    float4 wy4 = *reinterpret_cast<const float4*>(xb + 2 * T_LEN + k0);
    float4 wz4 = *reinterpret_cast<const float4*>(xb + 3 * T_LEN + k0);
    float4 ax4 = *reinterpret_cast<const float4*>(xb + 4 * T_LEN + k0);
    float4 ay4 = *reinterpret_cast<const float4*>(xb + 5 * T_LEN + k0);
    float4 az4 = *reinterpret_cast<const float4*>(xb + 6 * T_LEN + k0);

    float tv[5]  = {t4.x, t4.y, t4.z, t4.w, tn};
    float wxv[4] = {wx4.x, wx4.y, wx4.z, wx4.w};
    float wyv[4] = {wy4.x, wy4.y, wy4.z, wy4.w};
    float wzv[4] = {wz4.x, wz4.y, wz4.z, wz4.w};
    float axv[4] = {ax4.x, ax4.y, ax4.z, ax4.w};
    float ayv[4] = {ay4.x, ay4.y, ay4.z, ay4.w};
    float azv[4] = {az4.x, az4.y, az4.z, az4.w};

    // ---- local segment element, built by sequential stepping from identity ----
    float C0 = 1.f, C1 = 0.f, C2 = 0.f;
    float C3 = 0.f, C4 = 1.f, C5 = 0.f;
    float C6 = 0.f, C7 = 0.f, C8 = 1.f;
    float V0 = 0.f, V1 = 0.f, V2 = 0.f;
    float R0 = 0.f, R1 = 0.f, R2 = 0.f;
    float tau = 0.f;

#pragma unroll
    for (int j = 0; j < 4; ++j) {
        int k = k0 + j;
        if (k < NSTEP) {
            float dt = tv[j + 1] - tv[j];
            float ax = axv[j], ay = ayv[j], az = azv[j];
            // Ca = C * a
            float Ca0 = C0 * ax + C1 * ay + C2 * az;
            float Ca1 = C3 * ax + C4 * ay + C5 * az;
            float Ca2 = C6 * ax + C7 * ay + C8 * az;
            float h = 0.5f * dt * dt;
            R0 += V0 * dt + Ca0 * h;
            R1 += V1 * dt + Ca1 * h;
            R2 += V2 * dt + Ca2 * h;
            V0 += Ca0 * dt;
            V1 += Ca1 * dt;
            V2 += Ca2 * dt;
            float Rk[9];
            so3_exp(wxv[j] * dt, wyv[j] * dt, wzv[j] * dt, Rk);
            // C = C * Rk
            float n0 = C0 * Rk[0] + C1 * Rk[3] + C2 * Rk[6];
            float n1 = C0 * Rk[1] + C1 * Rk[4] + C2 * Rk[7];
            float n2 = C0 * Rk[2] + C1 * Rk[5] + C2 * Rk[8];
            float n3 = C3 * Rk[0] + C4 * Rk[3] + C5 * Rk[6];
            float n4 = C3 * Rk[1] + C4 * Rk[4] + C5 * Rk[7];
            float n5 = C3 * Rk[2] + C4 * Rk[5] + C5 * Rk[8];
            float n6 = C6 * Rk[0] + C7 * Rk[3] + C8 * Rk[6];
            float n7 = C6 * Rk[1] + C7 * Rk[4] + C8 * Rk[7];
            float n8 = C6 * Rk[2] + C7 * Rk[5] + C8 * Rk[8];
            C0 = n0; C1 = n1; C2 = n2;
            C3 = n3; C4 = n4; C5 = n5;
            C6 = n6; C7 = n7; C8 = n8;
            tau += dt;
        }
    }

    // ---- publish own element ----
    float* me = s + tid * 17;
    me[0] = C0; me[1] = C1; me[2] = C2;
    me[3] = C3; me[4] = C4; me[5] = C5;
    me[6] = C6; me[7] = C7; me[8] = C8;
    me[9]  = V0; me[10] = V1; me[11] = V2;
    me[12] = R0; me[13] = R1; me[14] = R2;
    me[15] = tau;

    // ---- adjacent-pair tree reduction (order-preserving) ----
    for (int str = 1; str < 256; str <<= 1) {
        __syncthreads();
        if ((tid & (2 * str - 1)) == 0) {
            const float* o = s + (tid + str) * 17;
            float M0 = o[0], M1 = o[1], M2 = o[2];
            float M3 = o[3], M4 = o[4], M5 = o[5];
            float M6 = o[6], M7 = o[7], M8 = o[8];
            float v0 = o[9], v1 = o[10], v2 = o[11];
            float r0 = o[12], r1 = o[13], r2 = o[14];
            float t2s = o[15];
            // r' = R + V*t2s + C*r
            float nr0 = R0 + V0 * t2s + C0 * r0 + C1 * r1 + C2 * r2;
            float nr1 = R1 + V1 * t2s + C3 * r0 + C4 * r1 + C5 * r2;
            float nr2 = R2 + V2 * t2s + C6 * r0 + C7 * r1 + C8 * r2;
            // v' = V + C*v
            float nv0 = V0 + C0 * v0 + C1 * v1 + C2 * v2;
            float nv1 = V1 + C3 * v0 + C4 * v1 + C5 * v2;
            float nv2 = V2 + C6 * v0 + C7 * v1 + C8 * v2;
            // M' = C * M
            float n0 = C0 * M0 + C1 * M3 + C2 * M6;
            float n1 = C0 * M1 + C1 * M4 + C2 * M7;
            float n2 = C0 * M2 + C1 * M5 + C2 * M8;
            float n3 = C3 * M0 + C4 * M3 + C5 * M6;
            float n4 = C3 * M1 + C4 * M4 + C5 * M7;
            float n5 = C3 * M2 + C4 * M5 + C5 * M8;
            float n6 = C6 * M0 + C7 * M3 + C8 * M6;
            float n7 = C6 * M1 + C7 * M4 + C8 * M7;
            float n8 = C6 * M2 + C7 * M5 + C8 * M8;
            C0 = n0; C1 = n1; C2 = n2;
            C3 = n3; C4 = n4; C5 = n5;
            C6 = n6; C7 = n7; C8 = n8;
            V0 = nv0; V1 = nv1; V2 = nv2;
            R0 = nr0; R1 = nr1; R2 = nr2;
            tau += t2s;
            me[0] = C0; me[1] = C1; me[2] = C2;
            me[3] = C3; me[4] = C4; me[5] = C5;
            me[6] = C6; me[7] = C7; me[8] = C8;
            me[9]  = V0; me[10] = V1; me[11] = V2;
            me[12] = R0; me[13] = R1; me[14] = R2;
            me[15] = tau;
        }
    }

    if (tid == 0) {
        float* ob = out + (size_t)b * 15;
        ob[0] = C0; ob[1] = C1; ob[2] = C2;
        ob[3] = C3; ob[4] = C4; ob[5] = C5;
        ob[6] = C6; ob[7] = C7; ob[8] = C8;
        ob[9]  = V0; ob[10] = V1; ob[11] = V2;
        ob[12] = R0; ob[13] = R1; ob[14] = R2;
    }
}

extern "C" void kernel_launch(void* const* d_in, const int* in_sizes, int n_in,
                              void* d_out, int out_size, void* d_ws, size_t ws_size,
                              hipStream_t stream) {
    const float* x = (const float*)d_in[0];
    float* out = (float*)d_out;
    const int B = in_sizes[0] / (7 * T_LEN);   // 4096
    rmi_kernel<<<B, 256, 0, stream>>>(x, out);
}